// Round 1
// baseline (652.763 us; speedup 1.0000x reference)
//
#include <hip/hip_runtime.h>
#include <math.h>

#define N_CLASSES 18
#define NMS_PRE   1000
#define K_NMS     500
#define POOL      4000      // 4 * NMS_PRE
#define LIST_CAP  2048
#define IOU_THR   0.5f
#define SCORE_THR 0.01f

struct Ptrs {
  const float* cent[4];
  const float* bbox[4];
  const float* cls[4];
  const float* pts[4];
  int off[4];   // flattened offsets: 0, n0, n0+n1, n0+n1+n2
  int ntot;
};

__device__ __forceinline__ unsigned int fsort(float f){
  unsigned int b = __float_as_uint(f);
  return (b & 0x80000000u) ? ~b : (b | 0x80000000u);
}
__device__ __forceinline__ float fsort_inv(unsigned int k){
  unsigned int b = (k & 0x80000000u) ? (k & 0x7FFFFFFFu) : ~k;
  return __uint_as_float(b);
}
__device__ __forceinline__ float sigmoidf_(float x){
  return 1.0f / (1.0f + expf(-x));
}
__device__ __forceinline__ int level_of(int f, const Ptrs& P){
  return (f >= P.off[3]) ? 3 : (f >= P.off[2]) ? 2 : (f >= P.off[1]) ? 1 : 0;
}

// In-LDS bitonic sort, descending by uint64 key. n = power of 2.
__device__ void bitonic_desc(unsigned long long* buf, int n){
  for (int k = 2; k <= n; k <<= 1){
    for (int j = k >> 1; j > 0; j >>= 1){
      __syncthreads();
      for (int i = threadIdx.x; i < n; i += blockDim.x){
        int ixj = i ^ j;
        if (ixj > i){
          unsigned long long a = buf[i], b = buf[ixj];
          bool do_swap = ((i & k) == 0) ? (a < b) : (a > b);
          if (do_swap){ buf[i] = b; buf[ixj] = a; }
        }
      }
    }
  }
  __syncthreads();
}

// ---------------- stage 0: init control state (ws is poisoned each call) ----
__global__ void init_kernel(unsigned int* hist, unsigned int* state, unsigned int* cnts){
  int t = threadIdx.x;
  if (t < 1024) hist[t] = 0;
  if (t < 4){ state[2*t + 0] = 0u; state[2*t + 1] = NMS_PRE; cnts[t] = 0u; }
}

// ---------------- stage 1: fused score max over classes -> sortable key -----
__global__ void compute_keys(Ptrs P, unsigned int* keys){
  int f = blockIdx.x * blockDim.x + threadIdx.x;
  if (f >= P.ntot) return;
  int L = level_of(f, P);
  int i = f - P.off[L];
  float cs = sigmoidf_(P.cent[L][i]);
  const float* cl = P.cls[L] + (size_t)i * N_CLASSES;
  float m = sigmoidf_(cl[0]) * cs;
#pragma unroll
  for (int c = 1; c < N_CLASSES; ++c)
    m = fmaxf(m, sigmoidf_(cl[c]) * cs);
  keys[f] = fsort(m);
}

// ---------------- stage 2: radix select (4 passes of 8 bits), per level -----
__global__ void radix_hist(Ptrs P, const unsigned int* keys, const unsigned int* state,
                           unsigned int* hist, int pass){
  __shared__ unsigned int lh[4][256];
  int t = threadIdx.x;
  for (int j = t; j < 1024; j += blockDim.x) (&lh[0][0])[j] = 0u;
  __syncthreads();
  int f = blockIdx.x * blockDim.x + t;
  if (f < P.ntot){
    int L = level_of(f, P);
    unsigned int key = keys[f];
    unsigned int prefix = state[2*L];
    int shift = 24 - 8*pass;
    // match the already-determined high bits (pass 0: everything matches)
    if (((unsigned long long)(key ^ prefix) >> (shift + 8)) == 0ull){
      atomicAdd(&lh[L][(key >> shift) & 0xFFu], 1u);
    }
  }
  __syncthreads();
  for (int j = t; j < 1024; j += blockDim.x){
    unsigned int v = (&lh[0][0])[j];
    if (v) atomicAdd(&hist[j], v);
  }
}

__global__ void radix_scan(unsigned int* hist, unsigned int* state, int pass){
  __shared__ unsigned int h[1024];
  int t = threadIdx.x;
  for (int j = t; j < 1024; j += blockDim.x) h[j] = hist[j];
  __syncthreads();
  if (t < 4){
    int L = t;
    unsigned int krem = state[2*L + 1];
    unsigned int prefix = state[2*L];
    int shift = 24 - 8*pass;
    unsigned int cacc = 0;
    for (int b = 255; b >= 0; --b){
      unsigned int cb = h[L*256 + b];
      if (cacc + cb >= krem){
        state[2*L]     = prefix | ((unsigned int)b << shift);
        state[2*L + 1] = krem - cacc;
        break;
      }
      cacc += cb;
    }
  }
  __syncthreads();
  for (int j = t; j < 1024; j += blockDim.x) hist[j] = 0u; // ready for next pass
}

// ---------------- stage 3: compact all keys >= T into per-level lists -------
__global__ void compact_kernel(Ptrs P, const unsigned int* keys, const unsigned int* state,
                               unsigned int* cnts, unsigned long long* lists){
  int f = blockIdx.x * blockDim.x + threadIdx.x;
  if (f >= P.ntot) return;
  int L = level_of(f, P);
  unsigned int key = keys[f];
  unsigned int T = state[2*L];   // after 4 passes: exact value of the 1000th largest
  if (key >= T){
    unsigned int pos = atomicAdd(&cnts[L], 1u);
    if (pos < LIST_CAP){
      unsigned int i = (unsigned int)(f - P.off[L]);
      // composite: (key desc, index asc) when sorted descending
      lists[(size_t)L*LIST_CAP + pos] =
        ((unsigned long long)key << 32) | (unsigned long long)(0xFFFFFFFFu - i);
    }
  }
}

// ---------------- stage 4: sort survivors, gather + decode top-1000 ---------
__global__ void __launch_bounds__(1024) sort_gather(Ptrs P, const unsigned long long* lists,
                                                    const unsigned int* cnts,
                                                    float* boxes_pool, float* scores_pool){
  __shared__ unsigned long long buf[LIST_CAP];
  int L = blockIdx.x;
  unsigned int cnt = cnts[L]; if (cnt > LIST_CAP) cnt = LIST_CAP;
  for (int j = threadIdx.x; j < LIST_CAP; j += blockDim.x)
    buf[j] = (j < (int)cnt) ? lists[(size_t)L*LIST_CAP + j] : 0ull;
  bitonic_desc(buf, LIST_CAP);
  if (threadIdx.x < NMS_PRE){
    int k = threadIdx.x;
    unsigned long long comp = buf[k];
    unsigned int i = 0xFFFFFFFFu - (unsigned int)(comp & 0xFFFFFFFFu);
    const float* bp = P.bbox[L] + (size_t)i * 6;
    const float* pp = P.pts[L]  + (size_t)i * 3;
    float p0 = bp[0], p1 = bp[1], p2 = bp[2], p3 = bp[3], p4 = bp[4], p5 = bp[5];
    float cx = pp[0] + (p1 - p0) * 0.5f;
    float cy = pp[1] + (p3 - p2) * 0.5f;
    float cz = pp[2] + (p5 - p4) * 0.5f;
    float w = p0 + p1, l = p2 + p3, h = p4 + p5;
    int r = L * NMS_PRE + k;             // matches jnp.concatenate order
    float* bo = boxes_pool + (size_t)r * 6;
    bo[0] = cx; bo[1] = cy; bo[2] = cz; bo[3] = w; bo[4] = l; bo[5] = h;
    float cs = sigmoidf_(P.cent[L][i]);
    const float* cl = P.cls[L] + (size_t)i * N_CLASSES;
#pragma unroll
    for (int c = 0; c < N_CLASSES; ++c)
      scores_pool[(size_t)c * POOL + r] = sigmoidf_(cl[c]) * cs;
  }
}

// ---------------- stage 5: per-class top-500 + write boxes/scores/labels ----
__global__ void __launch_bounds__(1024) class_topk(const float* scores_pool, const float* boxes_pool,
                                                   float* out, unsigned int* sel_idx, float* sel_sval){
  __shared__ unsigned long long buf[4096];
  int c = blockIdx.x;
  for (int j = threadIdx.x; j < 4096; j += blockDim.x){
    unsigned long long comp = 0ull;
    if (j < POOL){
      float s = scores_pool[(size_t)c * POOL + j];
      float sval = (s > SCORE_THR) ? s : -1.0f;   // matches jnp.where(valid, s, -1.0)
      comp = ((unsigned long long)fsort(sval) << 32)
           | (unsigned long long)(0xFFFFFFFFu - (unsigned int)j);
    }
    buf[j] = comp;
  }
  bitonic_desc(buf, 4096);
  if (threadIdx.x < K_NMS){
    int k = threadIdx.x;
    unsigned long long comp = buf[k];
    unsigned int j = 0xFFFFFFFFu - (unsigned int)(comp & 0xFFFFFFFFu);
    float sval = fsort_inv((unsigned int)(comp >> 32));
    int o = c * K_NMS + k;
    const float* bp = boxes_pool + (size_t)j * 6;
#pragma unroll
    for (int d = 0; d < 6; ++d) out[(size_t)o * 6 + d] = bp[d];       // b     [0,54000)
    out[54000 + o] = sval;                                            // sv    [54000,63000)
    out[63000 + o] = (float)c;                                        // label [63000,72000)
    sel_idx[o]  = j;
    sel_sval[o] = sval;
  }
}

// ---------------- stage 6: per-class NMS (mask + sequential greedy) ---------
__global__ void __launch_bounds__(512) nms_kernel(const float* boxes_pool, const unsigned int* sel_idx,
                                                  const float* sel_sval, float* keep_out){
  __shared__ float smn0[512], smn1[512], smn2[512];
  __shared__ float smx0[512], smx1[512], smx2[512];
  __shared__ float svol[512];
  __shared__ unsigned long long maskS[K_NMS][8];
  __shared__ unsigned long long vbits[8];
  __shared__ unsigned long long remS[8];
  int c = blockIdx.x;
  int t = threadIdx.x;
  int wave = t >> 6, lane = t & 63;

  float mn0 = 0.f, mn1 = 0.f, mn2 = 0.f, mx0 = 0.f, mx1 = 0.f, mx2 = 0.f;
  float vol = 0.f, sv = -1.0f;
  if (t < K_NMS){
    unsigned int j = sel_idx[c * K_NMS + t];
    const float* b = boxes_pool + (size_t)j * 6;
    float cx = b[0], cy = b[1], cz = b[2], ww = b[3], ll = b[4], hh = b[5];
    mn0 = cx - ww * 0.5f; mx0 = cx + ww * 0.5f;
    mn1 = cy - ll * 0.5f; mx1 = cy + ll * 0.5f;
    mn2 = cz - hh * 0.5f; mx2 = cz + hh * 0.5f;
    vol = fmaxf(mx0 - mn0, 0.f) * fmaxf(mx1 - mn1, 0.f) * fmaxf(mx2 - mn2, 0.f);
    sv = sel_sval[c * K_NMS + t];
  }
  smn0[t] = mn0; smn1[t] = mn1; smn2[t] = mn2;
  smx0[t] = mx0; smx1[t] = mx1; smx2[t] = mx2;
  svol[t] = vol;
  unsigned long long vb = __ballot(sv > SCORE_THR);
  if (lane == 0) vbits[wave] = vb;
  __syncthreads();

  for (int i = 0; i < K_NMS; ++i){
    float lt0 = fmaxf(smn0[i], mn0), lt1 = fmaxf(smn1[i], mn1), lt2 = fmaxf(smn2[i], mn2);
    float rb0 = fminf(smx0[i], mx0), rb1 = fminf(smx1[i], mx1), rb2 = fminf(smx2[i], mx2);
    float inter = fmaxf(rb0 - lt0, 0.f) * fmaxf(rb1 - lt1, 0.f) * fmaxf(rb2 - lt2, 0.f);
    float denom = svol[i] + vol - inter + 1e-6f;
    bool s = (t < K_NMS) && (t > i) && (inter / denom > IOU_THR);
    unsigned long long m = __ballot(s);
    if (lane == 0) maskS[i][wave] = m;
  }
  __syncthreads();

  if (wave == 0){
    // rem = suppressed bitset; init = ~valid (matches sup0 = !v)
    unsigned long long rem = (lane < 8) ? ~vbits[lane] : 0xFFFFFFFFFFFFFFFFull;
    for (int i = 0; i < K_NMS; ++i){
      unsigned long long wd = __shfl(rem, i >> 6);
      if (((wd >> (i & 63)) & 1ull) == 0ull){   // alive -> suppress its overlaps
        if (lane < 8) rem |= maskS[i][lane];
      }
    }
    if (lane < 8) remS[lane] = rem;
  }
  __syncthreads();
  for (int j = t; j < K_NMS; j += blockDim.x){
    bool sup = (remS[j >> 6] >> (j & 63)) & 1ull;
    keep_out[c * K_NMS + j] = sup ? 0.0f : 1.0f;  // keep = !sup (sup already includes !v)
  }
}

// ---------------------------------------------------------------------------
extern "C" void kernel_launch(void* const* d_in, const int* in_sizes, int n_in,
                              void* d_out, int out_size, void* d_ws, size_t ws_size,
                              hipStream_t stream){
  Ptrs P;
  int off = 0;
  for (int L = 0; L < 4; ++L){
    P.cent[L] = (const float*)d_in[4*L + 0];
    P.bbox[L] = (const float*)d_in[4*L + 1];
    P.cls[L]  = (const float*)d_in[4*L + 2];
    P.pts[L]  = (const float*)d_in[4*L + 3];
    P.off[L]  = off;
    off += in_sizes[4*L + 0];   // centerness has n elements
  }
  P.ntot = off;

  char* w = (char*)d_ws;
  size_t o = 0;
  unsigned int* keys = (unsigned int*)(w + o);
  o += ((size_t)P.ntot * 4 + 15) & ~(size_t)15;
  unsigned int* hist  = (unsigned int*)(w + o); o += 4 * 256 * 4;
  unsigned int* state = (unsigned int*)(w + o); o += 4 * 2 * 4;
  unsigned int* cnts  = (unsigned int*)(w + o); o += 32;
  unsigned long long* lists = (unsigned long long*)(w + o); o += (size_t)4 * LIST_CAP * 8;
  float* boxes_pool  = (float*)(w + o); o += (size_t)POOL * 6 * 4;
  float* scores_pool = (float*)(w + o); o += (size_t)N_CLASSES * POOL * 4;
  unsigned int* sel_idx = (unsigned int*)(w + o); o += (size_t)N_CLASSES * K_NMS * 4;
  float* sel_sval = (float*)(w + o); o += (size_t)N_CLASSES * K_NMS * 4;

  float* out = (float*)d_out;
  int grid = (P.ntot + 255) / 256;

  init_kernel<<<1, 1024, 0, stream>>>(hist, state, cnts);
  compute_keys<<<grid, 256, 0, stream>>>(P, keys);
  for (int pass = 0; pass < 4; ++pass){
    radix_hist<<<grid, 256, 0, stream>>>(P, keys, state, hist, pass);
    radix_scan<<<1, 256, 0, stream>>>(hist, state, pass);
  }
  compact_kernel<<<grid, 256, 0, stream>>>(P, keys, state, cnts, lists);
  sort_gather<<<4, 1024, 0, stream>>>(P, lists, cnts, boxes_pool, scores_pool);
  class_topk<<<N_CLASSES, 1024, 0, stream>>>(scores_pool, boxes_pool, out, sel_idx, sel_sval);
  nms_kernel<<<N_CLASSES, 512, 0, stream>>>(boxes_pool, sel_idx, sel_sval, out + 72000);
}

// Round 2
// 378.635 us; speedup vs baseline: 1.7240x; 1.7240x over previous
//
#include <hip/hip_runtime.h>
#include <math.h>

#define N_CLASSES 18
#define NMS_PRE   1000
#define K_NMS     500
#define POOL      4000      // 4 * NMS_PRE
#define LIST_CAP  2048
#define IOU_THR   0.5f
#define SCORE_THR 0.01f

struct Ptrs {
  const float* cent[4];
  const float* bbox[4];
  const float* cls[4];
  const float* pts[4];
  int off[4];
  int ntot;
};

__device__ __forceinline__ unsigned int fsort(float f){
  unsigned int b = __float_as_uint(f);
  return (b & 0x80000000u) ? ~b : (b | 0x80000000u);
}
__device__ __forceinline__ float fsort_inv(unsigned int k){
  unsigned int b = (k & 0x80000000u) ? (k & 0x7FFFFFFFu) : ~k;
  return __uint_as_float(b);
}
__device__ __forceinline__ float sigmoidf_(float x){
  return 1.0f / (1.0f + expf(-x));
}
__device__ __forceinline__ int level_of(int f, const Ptrs& P){
  return (f >= P.off[3]) ? 3 : (f >= P.off[2]) ? 2 : (f >= P.off[1]) ? 1 : 0;
}

// In-LDS bitonic sort, descending by uint64 key. n = power of 2. All threads
// of the block must call (threads >= n just participate in barriers).
__device__ void bitonic_desc(unsigned long long* buf, int n){
  for (int k = 2; k <= n; k <<= 1){
    for (int j = k >> 1; j > 0; j >>= 1){
      __syncthreads();
      for (int i = threadIdx.x; i < n; i += blockDim.x){
        int ixj = i ^ j;
        if (ixj > i){
          unsigned long long a = buf[i], b = buf[ixj];
          bool do_swap = ((i & k) == 0) ? (a < b) : (a > b);
          if (do_swap){ buf[i] = b; buf[ixj] = a; }
        }
      }
    }
  }
  __syncthreads();
}

// ---------------- stage 1: fused max-score key (+ control-state init) -------
__global__ void __launch_bounds__(256) compute_keys(Ptrs P, unsigned int* keys,
                        unsigned int* hist, unsigned int* state, unsigned int* cnts){
  if (blockIdx.x == 0){
    for (int j = threadIdx.x; j < 4*2048; j += 256) hist[j] = 0u;
    if (threadIdx.x < 4){
      state[2*threadIdx.x]   = 0u;
      state[2*threadIdx.x+1] = NMS_PRE;
      cnts[threadIdx.x]      = 0u;
    }
  }
  __shared__ float cls_s[256*19];   // row padded 18->19 (bank-conflict-free)
  int t = threadIdx.x;
  int f0 = blockIdx.x << 8;
  int f = f0 + t;
  float m = 0.f, cent = 0.f;
  bool valid = f < P.ntot;
  int fl = min(f0 + 255, P.ntot - 1);
  if (level_of(f0, P) == level_of(fl, P) && f0 + 255 < P.ntot){
    int L = level_of(f0, P);
    const float* base = P.cls[L] + (size_t)(f0 - P.off[L]) * N_CLASSES;
    const float4* base4 = (const float4*)base;      // 16B-aligned: f0*72 % 16 == 0
    for (int j = t; j < 256*N_CLASSES/4; j += 256){
      float4 v = base4[j];
      int e = 4*j;
      cls_s[((e  )/18)*19 + ((e  )%18)] = v.x;
      cls_s[((e+1)/18)*19 + ((e+1)%18)] = v.y;
      cls_s[((e+2)/18)*19 + ((e+2)%18)] = v.z;
      cls_s[((e+3)/18)*19 + ((e+3)%18)] = v.w;
    }
    __syncthreads();
    m = cls_s[t*19];
#pragma unroll
    for (int c = 1; c < N_CLASSES; ++c) m = fmaxf(m, cls_s[t*19 + c]);
    cent = P.cent[L][f - P.off[L]];
  } else {
    if (valid){
      int L = level_of(f, P); int i = f - P.off[L];
      const float* cl = P.cls[L] + (size_t)i * N_CLASSES;
      m = cl[0];
      for (int c = 1; c < N_CLASSES; ++c) m = fmaxf(m, cl[c]);
      cent = P.cent[L][i];
    }
  }
  if (valid){
    // sigmoid monotone in f32 + rounding monotone => sig(max)*sig(cent)
    // equals max_c(sig(c)*sig(cent)) exactly.
    float s = sigmoidf_(m) * sigmoidf_(cent);
    keys[f] = fsort(s);
  }
}

// ---------------- stage 2: 2-pass 11-bit level select ----------------------
__global__ void __launch_bounds__(256) hist_level(Ptrs P, const unsigned int* keys,
                        const unsigned int* state, unsigned int* hist, int pass){
  int t = threadIdx.x;
  int f0 = blockIdx.x << 8;
  int f = f0 + t;
  if (pass == 0){
    __shared__ unsigned int lh[2048];
    int fl = min(f0 + 255, P.ntot - 1);
    int Lb = level_of(f0, P);
    bool uni = (Lb == level_of(fl, P));
    for (int j = t; j < 2048; j += 256) lh[j] = 0u;
    __syncthreads();
    if (f < P.ntot){
      unsigned int bin = keys[f] >> 21;
      if (uni) atomicAdd(&lh[bin], 1u);
      else atomicAdd(&hist[level_of(f, P)*2048 + bin], 1u);
    }
    __syncthreads();
    if (uni){
      for (int j = t; j < 2048; j += 256){
        unsigned int v = lh[j];
        if (v) atomicAdd(&hist[Lb*2048 + j], v);
      }
    }
  } else {
    if (f < P.ntot){
      int L = level_of(f, P);
      unsigned int key = keys[f];
      unsigned int Pfx = state[2*L];
      if ((key >> 21) == (Pfx >> 21))
        atomicAdd(&hist[L*2048 + ((key >> 10) & 0x7FFu)], 1u);
    }
  }
}

__global__ void __launch_bounds__(256) scan_level(unsigned int* hist, unsigned int* state, int pass){
  int t = threadIdx.x;
  int w = t >> 6, lane = t & 63;
  // wave w handles level w: descending cumulative over 2048 bins
  {
    unsigned int krem = state[2*w + 1];
    unsigned int Pfx  = state[2*w];
    unsigned int carry = 0;
    for (int ch = 0; ch < 32; ++ch){
      int d = ch*64 + lane;               // descending rank
      unsigned int cnt = hist[w*2048 + (2047 - d)];
      unsigned int pfx = cnt;
#pragma unroll
      for (int off = 1; off < 64; off <<= 1){
        unsigned int u = __shfl_up(pfx, off);
        if (lane >= off) pfx += u;
      }
      unsigned int C = carry + pfx;
      unsigned long long bal = __ballot(C >= krem);
      if (bal){
        int fl2 = __ffsll(bal) - 1;
        unsigned int Cf = __shfl(C, fl2);
        unsigned int cf = __shfl(cnt, fl2);
        if (lane == 0){
          unsigned int b = (unsigned int)(2047 - (ch*64 + fl2));
          state[2*w]     = (pass == 0) ? (b << 21) : (Pfx | (b << 10));
          state[2*w + 1] = krem - (Cf - cf);
        }
        break;
      }
      carry = __shfl(C, 63);
    }
  }
  __syncthreads();
  for (int j = t; j < 4*2048; j += 256) hist[j] = 0u;   // ready for next pass
}

// ---------------- stage 3: compact keys >= T (22-bit-prefix lower bound) ----
__global__ void __launch_bounds__(256) compact_kernel(Ptrs P, const unsigned int* keys,
                        const unsigned int* state, unsigned int* cnts, unsigned long long* lists){
  int f = blockIdx.x * 256 + threadIdx.x;
  if (f >= P.ntot) return;
  int L = level_of(f, P);
  unsigned int key = keys[f];
  unsigned int T = state[2*L];
  if (key >= T){
    unsigned int pos = atomicAdd(&cnts[L], 1u);
    if (pos < LIST_CAP){
      unsigned int i = (unsigned int)(f - P.off[L]);
      lists[(size_t)L*LIST_CAP + pos] =
        ((unsigned long long)key << 32) | (unsigned long long)(~i);
    }
  }
}

// ---------------- stage 4a: sort survivors, emit sorted indices ------------
__global__ void __launch_bounds__(1024) sort_idx(const unsigned long long* lists,
                        const unsigned int* cnts, unsigned int* sidx){
  __shared__ unsigned long long buf[LIST_CAP];
  int L = blockIdx.x;
  unsigned int cnt = cnts[L]; if (cnt > LIST_CAP) cnt = LIST_CAP;
  int n = (cnt <= 1024) ? 1024 : LIST_CAP;
  for (int j = threadIdx.x; j < n; j += blockDim.x)
    buf[j] = (j < (int)cnt) ? lists[(size_t)L*LIST_CAP + j] : 0ull;
  bitonic_desc(buf, n);
  if (threadIdx.x < NMS_PRE)
    sidx[L*NMS_PRE + threadIdx.x] = ~((unsigned int)(buf[threadIdx.x] & 0xFFFFFFFFu));
}

// ---------------- stage 4b: gather + decode (wide grid for MLP) ------------
__global__ void __launch_bounds__(64) gather_decode(Ptrs P, const unsigned int* sidx,
                        float* boxes_pool, float* scores_pool){
  int r = blockIdx.x*64 + threadIdx.x;
  if (r >= POOL) return;
  int L = r / NMS_PRE;
  unsigned int i = sidx[r];
  const float* bp = P.bbox[L] + (size_t)i * 6;
  const float* pp = P.pts[L]  + (size_t)i * 3;
  float p0 = bp[0], p1 = bp[1], p2 = bp[2], p3 = bp[3], p4 = bp[4], p5 = bp[5];
  float cx = pp[0] + (p1 - p0) * 0.5f;
  float cy = pp[1] + (p3 - p2) * 0.5f;
  float cz = pp[2] + (p5 - p4) * 0.5f;
  float w = p0 + p1, l = p2 + p3, h = p4 + p5;
  float* bo = boxes_pool + (size_t)r * 6;
  bo[0] = cx; bo[1] = cy; bo[2] = cz; bo[3] = w; bo[4] = l; bo[5] = h;
  float cs = sigmoidf_(P.cent[L][i]);
  const float* cl = P.cls[L] + (size_t)i * N_CLASSES;
#pragma unroll
  for (int c = 0; c < N_CLASSES; ++c)
    scores_pool[(size_t)c * POOL + r] = sigmoidf_(cl[c]) * cs;
}

// ---------------- stage 5: per-class exact top-500 (radix select + sort512) -
__global__ void __launch_bounds__(1024) class_topk(const float* scores_pool, const float* boxes_pool,
                        float* out, float* aabb){
  __shared__ unsigned int keyS[4096];
  __shared__ unsigned long long comp[512];
  __shared__ unsigned int histS[256];
  __shared__ unsigned int wsum[16], wpre[16];
  __shared__ unsigned int sP, sK, sCnt;
  int c = blockIdx.x;
  int t = threadIdx.x;
  int w = t >> 6, lane = t & 63;

  for (int j = t; j < 4096; j += 1024){
    unsigned int k = 0u;
    if (j < POOL){
      float s = scores_pool[(size_t)c*POOL + j];
      float sval = (s > SCORE_THR) ? s : -1.0f;
      k = fsort(sval);
    }
    keyS[j] = k;
  }
  if (t == 0){ sP = 0u; sK = K_NMS; sCnt = 0u; }
  __syncthreads();

  // exact 500th-largest 32-bit key via 4x8-bit radix select
  for (int pass = 0; pass < 4; ++pass){
    int shift = 24 - 8*pass;
    if (t < 256) histS[t] = 0u;
    __syncthreads();
    unsigned int Pfx = sP;
    for (int j = t; j < 4096; j += 1024){
      unsigned int k = keyS[j];
      if ((((unsigned long long)(k ^ Pfx)) >> (shift + 8)) == 0ull)
        atomicAdd(&histS[(k >> shift) & 0xFFu], 1u);
    }
    __syncthreads();
    if (w == 0){
      unsigned int krem = sK;
      unsigned int carry = 0;
      for (int ch = 0; ch < 4; ++ch){
        unsigned int cnt = histS[255 - (ch*64 + lane)];
        unsigned int pfx = cnt;
#pragma unroll
        for (int off = 1; off < 64; off <<= 1){
          unsigned int u = __shfl_up(pfx, off);
          if (lane >= off) pfx += u;
        }
        unsigned int C = carry + pfx;
        unsigned long long bal = __ballot(C >= krem);
        if (bal){
          int fl = __ffsll(bal) - 1;
          unsigned int Cf = __shfl(C, fl);
          unsigned int cf = __shfl(cnt, fl);
          if (lane == 0){
            sP = Pfx | ((unsigned int)(255 - (ch*64 + fl)) << shift);
            sK = krem - (Cf - cf);
          }
          break;
        }
        carry = __shfl(C, 63);
      }
    }
    __syncthreads();
  }
  unsigned int T = sP, need = sK;

  // ordered tie rank: thread t owns j in [4t,4t+4), block prefix scan
  unsigned int loc[4]; unsigned int ct = 0;
#pragma unroll
  for (int q = 0; q < 4; ++q){
    unsigned int k = keyS[4*t + q];
    loc[q] = k;
    ct += (k == T) ? 1u : 0u;
  }
  unsigned int inc = ct;
#pragma unroll
  for (int off = 1; off < 64; off <<= 1){
    unsigned int u = __shfl_up(inc, off);
    if (lane >= off) inc += u;
  }
  if (lane == 63) wsum[w] = inc;
  __syncthreads();
  if (t < 16){
    unsigned int v = wsum[t];
    unsigned int pincl = v;
#pragma unroll
    for (int off = 1; off < 16; off <<= 1){
      unsigned int u = __shfl_up(pincl, off);
      if (t >= off) pincl += u;
    }
    wpre[t] = pincl - v;
  }
  __syncthreads();
  unsigned int excl = wpre[w] + (inc - ct);

  // compact exactly 500 survivors: key>T, plus ties (==T) in index order
#pragma unroll
  for (int q = 0; q < 4; ++q){
    unsigned int k = loc[q];
    bool surv = false;
    if (k > T) surv = true;
    else if (k == T){ surv = (excl < need); excl += 1u; }
    if (surv){
      unsigned int pos = atomicAdd(&sCnt, 1u);
      if (pos < 512)
        comp[pos] = ((unsigned long long)k << 32) | (unsigned long long)(~(unsigned int)(4*t + q));
    }
  }
  __syncthreads();
  for (int j = t; j < 512; j += 1024) if (j >= (int)sCnt) comp[j] = 0ull;
  bitonic_desc(comp, 512);

  if (t < K_NMS){
    unsigned long long cm = comp[t];
    unsigned int j = ~((unsigned int)(cm & 0xFFFFFFFFu));
    float sval = fsort_inv((unsigned int)(cm >> 32));
    int o = c*K_NMS + t;
    const float* bp = boxes_pool + (size_t)j * 6;
    float b0 = bp[0], b1 = bp[1], b2 = bp[2], b3 = bp[3], b4 = bp[4], b5 = bp[5];
    float* ob = out + (size_t)o * 6;
    ob[0] = b0; ob[1] = b1; ob[2] = b2; ob[3] = b3; ob[4] = b4; ob[5] = b5;
    out[54000 + o] = sval;
    out[63000 + o] = (float)c;
    float mn0 = b0 - b3*0.5f, mx0 = b0 + b3*0.5f;
    float mn1 = b1 - b4*0.5f, mx1 = b1 + b4*0.5f;
    float mn2 = b2 - b5*0.5f, mx2 = b2 + b5*0.5f;
    float vol = fmaxf(mx0 - mn0, 0.f) * fmaxf(mx1 - mn1, 0.f) * fmaxf(mx2 - mn2, 0.f);
    float* ap = aabb + ((size_t)c*512 + t) * 8;
    ap[0] = mn0; ap[1] = mn1; ap[2] = mn2; ap[3] = mx0; ap[4] = mx1; ap[5] = mx2;
    ap[6] = vol; ap[7] = sval;
  }
}

// ---------------- stage 6a: NMS suppression-mask build (parallel rows) ------
__global__ void __launch_bounds__(512) nms_mask(const float* aabb, unsigned long long* maskG){
  __shared__ float smn0[512], smn1[512], smn2[512];
  __shared__ float smx0[512], smx1[512], smx2[512];
  __shared__ float svol[512];
  int c = blockIdx.y, chunk = blockIdx.x;
  int t = threadIdx.x, w = t >> 6, lane = t & 63;
  float mn0 = 0.f, mn1 = 0.f, mn2 = 0.f, mx0 = 0.f, mx1 = 0.f, mx2 = 0.f, vol = 0.f;
  if (t < K_NMS){
    const float* ap = aabb + ((size_t)c*512 + t) * 8;
    mn0 = ap[0]; mn1 = ap[1]; mn2 = ap[2];
    mx0 = ap[3]; mx1 = ap[4]; mx2 = ap[5]; vol = ap[6];
  }
  smn0[t] = mn0; smn1[t] = mn1; smn2[t] = mn2;
  smx0[t] = mx0; smx1[t] = mx1; smx2[t] = mx2;
  svol[t] = vol;
  __syncthreads();
  int i0 = chunk * 64, i1 = min(i0 + 64, K_NMS);
  for (int i = i0; i < i1; ++i){
    float lt0 = fmaxf(smn0[i], mn0), lt1 = fmaxf(smn1[i], mn1), lt2 = fmaxf(smn2[i], mn2);
    float rb0 = fminf(smx0[i], mx0), rb1 = fminf(smx1[i], mx1), rb2 = fminf(smx2[i], mx2);
    float inter = fmaxf(rb0 - lt0, 0.f) * fmaxf(rb1 - lt1, 0.f) * fmaxf(rb2 - lt2, 0.f);
    float denom = svol[i] + vol - inter + 1e-6f;
    bool s = (t < K_NMS) && (t > i) && (inter / denom > IOU_THR);
    unsigned long long m = __ballot(s);
    if (lane == 0) maskG[((size_t)c*K_NMS + i)*8 + w] = m;
  }
}

// ---------------- stage 6b: greedy pass (short dependent chain, prefetched) -
__global__ void __launch_bounds__(512) nms_greedy(const float* aabb, const unsigned long long* maskG,
                        float* keep_out){
  __shared__ unsigned long long maskS[K_NMS*8];
  __shared__ unsigned long long vbits[8], remS[8];
  int c = blockIdx.x, t = threadIdx.x, w = t >> 6, lane = t & 63;
  for (int j = t; j < K_NMS*8; j += 512) maskS[j] = maskG[(size_t)c*K_NMS*8 + j];
  float sv = (t < K_NMS) ? aabb[((size_t)c*512 + t)*8 + 7] : -1.0f;
  unsigned long long vb = __ballot(sv > SCORE_THR);
  if (lane == 0) vbits[w] = vb;
  __syncthreads();
  if (w == 0){
    unsigned long long rem = (lane < 8) ? ~vbits[lane] : ~0ull;   // sup0 = !valid
    unsigned long long mnext = (lane < 8) ? maskS[lane] : 0ull;
    for (int i = 0; i < K_NMS; ++i){
      unsigned long long mcur = mnext;
      if (i + 1 < K_NMS) mnext = (lane < 8) ? maskS[(i+1)*8 + lane] : 0ull;
      unsigned long long wd = __shfl(rem, i >> 6);
      if (((wd >> (i & 63)) & 1ull) == 0ull){        // box i alive
        if (lane < 8) rem |= mcur;
      }
    }
    if (lane < 8) remS[lane] = rem;
  }
  __syncthreads();
  if (t < K_NMS)
    keep_out[c*K_NMS + t] = ((remS[t >> 6] >> (t & 63)) & 1ull) ? 0.0f : 1.0f;
}

// ---------------------------------------------------------------------------
extern "C" void kernel_launch(void* const* d_in, const int* in_sizes, int n_in,
                              void* d_out, int out_size, void* d_ws, size_t ws_size,
                              hipStream_t stream){
  Ptrs P;
  int off = 0;
  for (int L = 0; L < 4; ++L){
    P.cent[L] = (const float*)d_in[4*L + 0];
    P.bbox[L] = (const float*)d_in[4*L + 1];
    P.cls[L]  = (const float*)d_in[4*L + 2];
    P.pts[L]  = (const float*)d_in[4*L + 3];
    P.off[L]  = off;
    off += in_sizes[4*L + 0];
  }
  P.ntot = off;

  char* w = (char*)d_ws;
  size_t o = 0;
  auto alloc = [&](size_t bytes) -> char* {
    char* p = w + o;
    o = (o + bytes + 255) & ~(size_t)255;
    return p;
  };
  unsigned int* keys        = (unsigned int*)alloc((size_t)P.ntot * 4);
  unsigned int* hist        = (unsigned int*)alloc(4 * 2048 * 4);
  unsigned int* state       = (unsigned int*)alloc(4 * 2 * 4);
  unsigned int* cnts        = (unsigned int*)alloc(4 * 4);
  unsigned long long* lists = (unsigned long long*)alloc((size_t)4 * LIST_CAP * 8);
  unsigned int* sidx        = (unsigned int*)alloc((size_t)POOL * 4);
  float* boxes_pool         = (float*)alloc((size_t)POOL * 6 * 4);
  float* scores_pool        = (float*)alloc((size_t)N_CLASSES * POOL * 4);
  float* aabb               = (float*)alloc((size_t)N_CLASSES * 512 * 8 * 4);
  unsigned long long* maskG = (unsigned long long*)alloc((size_t)N_CLASSES * K_NMS * 8 * 8);

  float* out = (float*)d_out;
  int grid = (P.ntot + 255) / 256;

  compute_keys<<<grid, 256, 0, stream>>>(P, keys, hist, state, cnts);
  hist_level<<<grid, 256, 0, stream>>>(P, keys, state, hist, 0);
  scan_level<<<1, 256, 0, stream>>>(hist, state, 0);
  hist_level<<<grid, 256, 0, stream>>>(P, keys, state, hist, 1);
  scan_level<<<1, 256, 0, stream>>>(hist, state, 1);
  compact_kernel<<<grid, 256, 0, stream>>>(P, keys, state, cnts, lists);
  sort_idx<<<4, 1024, 0, stream>>>(lists, cnts, sidx);
  gather_decode<<<(POOL + 63)/64, 64, 0, stream>>>(P, sidx, boxes_pool, scores_pool);
  class_topk<<<N_CLASSES, 1024, 0, stream>>>(scores_pool, boxes_pool, out, aabb);
  nms_mask<<<dim3(8, N_CLASSES), 512, 0, stream>>>(aabb, maskG);
  nms_greedy<<<N_CLASSES, 512, 0, stream>>>(aabb, maskG, out + 72000);
}

// Round 4
// 312.654 us; speedup vs baseline: 2.0878x; 1.2110x over previous
//
#include <hip/hip_runtime.h>
#include <math.h>

#define N_CLASSES 18
#define NMS_PRE   1000
#define K_NMS     500
#define POOL      4000      // 4 * NMS_PRE
#define LIST_CAP  2048
#define IOU_THR   0.5f
#define SCORE_THR 0.01f

typedef unsigned long long ull;

struct Ptrs {
  const float* cent[4];
  const float* bbox[4];
  const float* cls[4];
  const float* pts[4];
  int off[4];
  int ntot;
};

__device__ __forceinline__ unsigned int fsort(float f){
  unsigned int b = __float_as_uint(f);
  return (b & 0x80000000u) ? ~b : (b | 0x80000000u);
}
__device__ __forceinline__ float fsort_inv(unsigned int k){
  unsigned int b = (k & 0x80000000u) ? (k & 0x7FFFFFFFu) : ~k;
  return __uint_as_float(b);
}
__device__ __forceinline__ float sigmoidf_(float x){
  return 1.0f / (1.0f + expf(-x));
}
__device__ __forceinline__ int level_of(int f, const Ptrs& P){
  return (f >= P.off[3]) ? 3 : (f >= P.off[2]) ? 2 : (f >= P.off[1]) ? 1 : 0;
}

// compare-exchange helpers for hybrid bitonic (desc).
__device__ __forceinline__ ull cx_keep(ull mine, ull part, bool keep_hi){
  ull mx = mine > part ? mine : part;
  ull mn = mine > part ? part : mine;
  return keep_hi ? mx : mn;
}
__device__ __forceinline__ void cxpair(ull &a, ull &b, bool a_hi){
  ull mx = a > b ? a : b;
  ull mn = a > b ? b : a;
  a = a_hi ? mx : mn;
  b = a_hi ? mn : mx;
}

// ---------------- stage 0: zero control state (ws poisoned every call) ------
__global__ void __launch_bounds__(256) init_kernel(unsigned int* hist, unsigned int* state,
                        unsigned int* cnts){
  for (int j = threadIdx.x; j < 4*2048; j += 256) hist[j] = 0u;
  if (threadIdx.x < 4){
    state[2*threadIdx.x]   = 0u;
    state[2*threadIdx.x+1] = NMS_PRE;
    cnts[threadIdx.x]      = 0u;
  }
}

// ---------------- stage 1: fused max-score key + pass-0 histogram -----------
__global__ void __launch_bounds__(256) compute_keys(Ptrs P, unsigned int* keys,
                        unsigned int* hist){
  __shared__ float cls_s[256*19];   // row padded 18->19
  __shared__ unsigned int lh[2048];
  int t = threadIdx.x;
  for (int j = t; j < 2048; j += 256) lh[j] = 0u;
  int f0 = blockIdx.x << 8;
  int f = f0 + t;
  float m = 0.f, cent = 0.f;
  bool valid = f < P.ntot;
  int fl = min(f0 + 255, P.ntot - 1);
  bool uni = (level_of(f0, P) == level_of(fl, P)) && (f0 + 255 < P.ntot);
  int Lb = level_of(f0, P);
  if (uni){
    const float* base = P.cls[Lb] + (size_t)(f0 - P.off[Lb]) * N_CLASSES;
    const float4* base4 = (const float4*)base;    // f0*72 bytes, 16B aligned
    for (int j = t; j < 256*N_CLASSES/4; j += 256){
      float4 v = base4[j];
      int e = 4*j;
      cls_s[((e  )/18)*19 + ((e  )%18)] = v.x;
      cls_s[((e+1)/18)*19 + ((e+1)%18)] = v.y;
      cls_s[((e+2)/18)*19 + ((e+2)%18)] = v.z;
      cls_s[((e+3)/18)*19 + ((e+3)%18)] = v.w;
    }
    __syncthreads();
    m = cls_s[t*19];
#pragma unroll
    for (int c = 1; c < N_CLASSES; ++c) m = fmaxf(m, cls_s[t*19 + c]);
    cent = P.cent[Lb][f - P.off[Lb]];
  } else {
    __syncthreads();
    if (valid){
      int L = level_of(f, P); int i = f - P.off[L];
      const float* cl = P.cls[L] + (size_t)i * N_CLASSES;
      m = cl[0];
      for (int c = 1; c < N_CLASSES; ++c) m = fmaxf(m, cl[c]);
      cent = P.cent[L][i];
    }
  }
  if (valid){
    // sigmoid monotone => sig(max)*sig(cent) == max_c(sig(c)*sig(cent))
    float s = sigmoidf_(m) * sigmoidf_(cent);
    unsigned int key = fsort(s);
    keys[f] = key;
    unsigned int bin = key >> 21;
    if (uni) atomicAdd(&lh[bin], 1u);
    else     atomicAdd(&hist[level_of(f, P)*2048 + bin], 1u);
  }
  __syncthreads();
  if (uni){
    for (int j = t; j < 2048; j += 256){
      unsigned int v = lh[j];
      if (v) atomicAdd(&hist[Lb*2048 + j], v);
    }
  }
}

// ---------------- stage 2: second 11-bit histogram pass ---------------------
__global__ void __launch_bounds__(256) hist_level(Ptrs P, const unsigned int* keys,
                        const unsigned int* state, unsigned int* hist){
  int f = blockIdx.x * 256 + threadIdx.x;
  if (f < P.ntot){
    int L = level_of(f, P);
    unsigned int key = keys[f];
    unsigned int Pfx = state[2*L];
    if ((key >> 21) == (Pfx >> 21))
      atomicAdd(&hist[L*2048 + ((key >> 10) & 0x7FFu)], 1u);
  }
}

__global__ void __launch_bounds__(256) scan_level(unsigned int* hist, unsigned int* state, int pass){
  __shared__ unsigned int lhist[4*2048];
  int t = threadIdx.x;
  int w = t >> 6, lane = t & 63;
  for (int j = t; j < 4*2048; j += 256) lhist[j] = hist[j];
  __syncthreads();
  {
    unsigned int krem = state[2*w + 1];
    unsigned int Pfx  = state[2*w];
    unsigned int carry = 0;
    for (int ch = 0; ch < 32; ++ch){
      int d = ch*64 + lane;               // descending rank
      unsigned int cnt = lhist[w*2048 + (2047 - d)];
      unsigned int pfx = cnt;
#pragma unroll
      for (int off = 1; off < 64; off <<= 1){
        unsigned int u = __shfl_up(pfx, off);
        if (lane >= off) pfx += u;
      }
      unsigned int C = carry + pfx;
      ull bal = __ballot(C >= krem);
      if (bal){
        int fl2 = __ffsll(bal) - 1;
        unsigned int Cf = __shfl(C, fl2);
        unsigned int cf = __shfl(cnt, fl2);
        if (lane == 0){
          unsigned int b = (unsigned int)(2047 - (ch*64 + fl2));
          state[2*w]     = (pass == 0) ? (b << 21) : (Pfx | (b << 10));
          state[2*w + 1] = krem - (Cf - cf);
        }
        break;
      }
      carry = __shfl(C, 63);
    }
  }
  if (pass == 0){
    __syncthreads();
    for (int j = t; j < 4*2048; j += 256) hist[j] = 0u;   // ready for pass 1
  }
}

// ---------------- stage 3: compact keys >= T (22-bit-prefix lower bound) ----
__global__ void __launch_bounds__(256) compact_kernel(Ptrs P, const unsigned int* keys,
                        const unsigned int* state, unsigned int* cnts, ull* lists){
  int f = blockIdx.x * 256 + threadIdx.x;
  if (f >= P.ntot) return;
  int L = level_of(f, P);
  unsigned int key = keys[f];
  unsigned int T = state[2*L];
  if (key >= T){
    unsigned int pos = atomicAdd(&cnts[L], 1u);
    if (pos < LIST_CAP){
      unsigned int i = (unsigned int)(f - P.off[L]);
      lists[(size_t)L*LIST_CAP + pos] = ((ull)key << 32) | (ull)(~i);
    }
  }
}

// ---------------- stage 4a: hybrid bitonic sort -> sorted indices -----------
// Stages j<64 via __shfl_xor (register, race-free); j>=64 via LDS with full
// barriers (each thread writes ONLY its own elements, then barrier, then
// reads partner — no cross-wave write hazard).
__global__ void __launch_bounds__(1024) sort_idx(const ull* lists,
                        const unsigned int* cnts, unsigned int* sidx){
  __shared__ ull buf[LIST_CAP];
  int L = blockIdx.x;
  int t = threadIdx.x;
  unsigned int cnt = cnts[L]; if (cnt > LIST_CAP) cnt = LIST_CAP;
  const ull* src = lists + (size_t)L*LIST_CAP;
  if (cnt <= 1024u){
    ull v0 = (t < (int)cnt) ? src[t] : 0ull;
    for (int k = 2; k <= 1024; k <<= 1){
      for (int j = k >> 1; j > 0; j >>= 1){
        bool hi0 = (((t & j) == 0) == ((t & k) == 0));
        if (j >= 64){
          __syncthreads();
          buf[t] = v0;
          __syncthreads();
          ull p0 = buf[t ^ j];
          v0 = cx_keep(v0, p0, hi0);
        } else {
          ull p0 = __shfl_xor(v0, j);
          v0 = cx_keep(v0, p0, hi0);
        }
      }
    }
    if (t < NMS_PRE) sidx[L*NMS_PRE + t] = ~((unsigned int)(v0 & 0xFFFFFFFFu));
  } else {
    int e1 = t + 1024;
    ull v0 = (t  < (int)cnt) ? src[t]  : 0ull;
    ull v1 = (e1 < (int)cnt) ? src[e1] : 0ull;
    for (int k = 2; k <= 2048; k <<= 1){
      for (int j = k >> 1; j > 0; j >>= 1){
        bool hi0 = (((t  & j) == 0) == ((t  & k) == 0));
        bool hi1 = (((e1 & j) == 0) == ((e1 & k) == 0));
        if (j >= 1024){
          cxpair(v0, v1, hi0);           // partner is own second element
        } else if (j >= 64){
          __syncthreads();
          buf[t] = v0; buf[e1] = v1;
          __syncthreads();
          ull p0 = buf[t ^ j];
          ull p1 = buf[e1 ^ j];
          v0 = cx_keep(v0, p0, hi0);
          v1 = cx_keep(v1, p1, hi1);
        } else {
          ull p0 = __shfl_xor(v0, j);
          ull p1 = __shfl_xor(v1, j);
          v0 = cx_keep(v0, p0, hi0);
          v1 = cx_keep(v1, p1, hi1);
        }
      }
    }
    if (t < NMS_PRE) sidx[L*NMS_PRE + t] = ~((unsigned int)(v0 & 0xFFFFFFFFu));
  }
}

// ---------------- stage 4b: gather + decode (wide grid for MLP) ------------
__global__ void __launch_bounds__(64) gather_decode(Ptrs P, const unsigned int* sidx,
                        float* boxes_pool, float* scores_pool){
  int r = blockIdx.x*64 + threadIdx.x;
  if (r >= POOL) return;
  int L = r / NMS_PRE;
  unsigned int i = sidx[r];
  const float* bp = P.bbox[L] + (size_t)i * 6;
  const float* pp = P.pts[L]  + (size_t)i * 3;
  float p0 = bp[0], p1 = bp[1], p2 = bp[2], p3 = bp[3], p4 = bp[4], p5 = bp[5];
  float cx = pp[0] + (p1 - p0) * 0.5f;
  float cy = pp[1] + (p3 - p2) * 0.5f;
  float cz = pp[2] + (p5 - p4) * 0.5f;
  float w = p0 + p1, l = p2 + p3, h = p4 + p5;
  float* bo = boxes_pool + (size_t)r * 6;
  bo[0] = cx; bo[1] = cy; bo[2] = cz; bo[3] = w; bo[4] = l; bo[5] = h;
  float cs = sigmoidf_(P.cent[L][i]);
  const float* cl = P.cls[L] + (size_t)i * N_CLASSES;
#pragma unroll
  for (int c = 0; c < N_CLASSES; ++c)
    scores_pool[(size_t)c * POOL + r] = sigmoidf_(cl[c]) * cs;
}

// ---------------- stage 5: per-class exact top-500 (radix select + sort512) -
__global__ void __launch_bounds__(1024) class_topk(const float* scores_pool, const float* boxes_pool,
                        float* out, float* aabb){
  __shared__ unsigned int keyS[4096];
  __shared__ ull comp[512];
  __shared__ unsigned int histS[256];
  __shared__ unsigned int wsum[16], wpre[16];
  __shared__ unsigned int sP, sK, sCnt;
  int c = blockIdx.x;
  int t = threadIdx.x;
  int w = t >> 6, lane = t & 63;

  for (int j = t; j < 4096; j += 1024){
    unsigned int k = 0u;
    if (j < POOL){
      float s = scores_pool[(size_t)c*POOL + j];
      float sval = (s > SCORE_THR) ? s : -1.0f;
      k = fsort(sval);
    }
    keyS[j] = k;
  }
  if (t == 0){ sP = 0u; sK = K_NMS; sCnt = 0u; }
  __syncthreads();

  // exact 500th-largest key via 4x8-bit radix select
  for (int pass = 0; pass < 4; ++pass){
    int shift = 24 - 8*pass;
    if (t < 256) histS[t] = 0u;
    __syncthreads();
    unsigned int Pfx = sP;
    for (int j = t; j < 4096; j += 1024){
      unsigned int k = keyS[j];
      if ((((ull)(k ^ Pfx)) >> (shift + 8)) == 0ull)
        atomicAdd(&histS[(k >> shift) & 0xFFu], 1u);
    }
    __syncthreads();
    if (w == 0){
      unsigned int krem = sK;
      unsigned int carry = 0;
      for (int ch = 0; ch < 4; ++ch){
        unsigned int cnt = histS[255 - (ch*64 + lane)];
        unsigned int pfx = cnt;
#pragma unroll
        for (int off = 1; off < 64; off <<= 1){
          unsigned int u = __shfl_up(pfx, off);
          if (lane >= off) pfx += u;
        }
        unsigned int C = carry + pfx;
        ull bal = __ballot(C >= krem);
        if (bal){
          int fl = __ffsll(bal) - 1;
          unsigned int Cf = __shfl(C, fl);
          unsigned int cf = __shfl(cnt, fl);
          if (lane == 0){
            sP = Pfx | ((unsigned int)(255 - (ch*64 + fl)) << shift);
            sK = krem - (Cf - cf);
          }
          break;
        }
        carry = __shfl(C, 63);
      }
    }
    __syncthreads();
  }
  unsigned int T = sP, need = sK;

  // ordered tie rank via block prefix scan; thread t owns keyS[4t..4t+4)
  unsigned int loc[4]; unsigned int ct = 0;
#pragma unroll
  for (int q = 0; q < 4; ++q){
    unsigned int k = keyS[4*t + q];
    loc[q] = k;
    ct += (k == T) ? 1u : 0u;
  }
  unsigned int inc = ct;
#pragma unroll
  for (int off = 1; off < 64; off <<= 1){
    unsigned int u = __shfl_up(inc, off);
    if (lane >= off) inc += u;
  }
  if (lane == 63) wsum[w] = inc;
  __syncthreads();
  if (t < 16){
    unsigned int v = wsum[t];
    unsigned int pincl = v;
#pragma unroll
    for (int off = 1; off < 16; off <<= 1){
      unsigned int u = __shfl_up(pincl, off);
      if (t >= off) pincl += u;
    }
    wpre[t] = pincl - v;
  }
  __syncthreads();
  unsigned int excl = wpre[w] + (inc - ct);

  // compact exactly 500 survivors: key>T, plus ==T ties in index order
#pragma unroll
  for (int q = 0; q < 4; ++q){
    unsigned int k = loc[q];
    bool surv = false;
    if (k > T) surv = true;
    else if (k == T){ surv = (excl < need); excl += 1u; }
    if (surv){
      unsigned int pos = atomicAdd(&sCnt, 1u);
      if (pos < 512)
        comp[pos] = ((ull)k << 32) | (ull)(~(unsigned int)(4*t + q));
    }
  }
  __syncthreads();

  // hybrid bitonic desc over 512 elements (threads t<512 own elem t)
  ull v0 = 0ull;
  if (t < 512 && t < (int)sCnt) v0 = comp[t];
  for (int k = 2; k <= 512; k <<= 1){
    for (int j = k >> 1; j > 0; j >>= 1){
      if (j >= 64){
        __syncthreads();
        if (t < 512) comp[t] = v0;
        __syncthreads();
        if (t < 512){
          ull p0 = comp[t ^ j];
          bool hi0 = (((t & j) == 0) == ((t & k) == 0));
          v0 = cx_keep(v0, p0, hi0);
        }
      } else {
        if (t < 512){
          ull p0 = __shfl_xor(v0, j);
          bool hi0 = (((t & j) == 0) == ((t & k) == 0));
          v0 = cx_keep(v0, p0, hi0);
        }
      }
    }
  }

  if (t < K_NMS){
    ull cm = v0;
    unsigned int j = ~((unsigned int)(cm & 0xFFFFFFFFu));
    float sval = fsort_inv((unsigned int)(cm >> 32));
    int o = c*K_NMS + t;
    const float* bp = boxes_pool + (size_t)j * 6;
    float b0 = bp[0], b1 = bp[1], b2 = bp[2], b3 = bp[3], b4 = bp[4], b5 = bp[5];
    float* ob = out + (size_t)o * 6;
    ob[0] = b0; ob[1] = b1; ob[2] = b2; ob[3] = b3; ob[4] = b4; ob[5] = b5;
    out[54000 + o] = sval;
    out[63000 + o] = (float)c;
    float mn0 = b0 - b3*0.5f, mx0 = b0 + b3*0.5f;
    float mn1 = b1 - b4*0.5f, mx1 = b1 + b4*0.5f;
    float mn2 = b2 - b5*0.5f, mx2 = b2 + b5*0.5f;
    float vol = fmaxf(mx0 - mn0, 0.f) * fmaxf(mx1 - mn1, 0.f) * fmaxf(mx2 - mn2, 0.f);
    float* ap = aabb + ((size_t)c*512 + t) * 8;
    ap[0] = mn0; ap[1] = mn1; ap[2] = mn2; ap[3] = mx0; ap[4] = mx1; ap[5] = mx2;
    ap[6] = vol; ap[7] = sval;
  }
}

// ---------------- stage 6a: NMS mask build + per-row nonzero flags ----------
__global__ void __launch_bounds__(512) nms_mask(const float* aabb, ull* maskG, ull* flagsG){
  __shared__ float smn0[512], smn1[512], smn2[512];
  __shared__ float smx0[512], smx1[512], smx2[512];
  __shared__ float svol[512];
  __shared__ ull rowbuf[64*8];
  int c = blockIdx.y, chunk = blockIdx.x;
  int t = threadIdx.x, w = t >> 6, lane = t & 63;
  float mn0 = 0.f, mn1 = 0.f, mn2 = 0.f, mx0 = 0.f, mx1 = 0.f, mx2 = 0.f, vol = 0.f;
  if (t < K_NMS){
    const float* ap = aabb + ((size_t)c*512 + t) * 8;
    mn0 = ap[0]; mn1 = ap[1]; mn2 = ap[2];
    mx0 = ap[3]; mx1 = ap[4]; mx2 = ap[5]; vol = ap[6];
  }
  smn0[t] = mn0; smn1[t] = mn1; smn2[t] = mn2;
  smx0[t] = mx0; smx1[t] = mx1; smx2[t] = mx2;
  svol[t] = vol;
  __syncthreads();
  int i0 = chunk * 64, i1 = min(i0 + 64, K_NMS);
  for (int i = i0; i < i1; ++i){
    float lt0 = fmaxf(smn0[i], mn0), lt1 = fmaxf(smn1[i], mn1), lt2 = fmaxf(smn2[i], mn2);
    float rb0 = fminf(smx0[i], mx0), rb1 = fminf(smx1[i], mx1), rb2 = fminf(smx2[i], mx2);
    float inter = fmaxf(rb0 - lt0, 0.f) * fmaxf(rb1 - lt1, 0.f) * fmaxf(rb2 - lt2, 0.f);
    float denom = svol[i] + vol - inter + 1e-6f;
    bool s = (t < K_NMS) && (t > i) && (inter / denom > IOU_THR);
    ull m = __ballot(s);
    if (lane == 0){
      maskG[((size_t)c*K_NMS + i)*8 + w] = m;
      rowbuf[(i - i0)*8 + w] = m;
    }
  }
  __syncthreads();
  if (t < 64){
    int r = i0 + t;
    bool nz = false;
    if (r < K_NMS){
      ull o = 0ull;
#pragma unroll
      for (int z = 0; z < 8; ++z) o |= rowbuf[t*8 + z];
      nz = (o != 0ull);
    }
    ull bal = __ballot(nz);
    if (t == 0) flagsG[(size_t)c*8 + chunk] = bal;
  }
}

// ---------------- stage 6b: greedy — replicated bitset + event skipping -----
__global__ void __launch_bounds__(512) nms_greedy(const float* aabb, const ull* maskG,
                        const ull* flagsG, float* keep_out){
  __shared__ ull maskS[K_NMS*8];
  __shared__ ull vbitsS[8], remS[8];
  int c = blockIdx.x, t = threadIdx.x, w = t >> 6, lane = t & 63;
  ull flg[8];
#pragma unroll
  for (int q = 0; q < 8; ++q) flg[q] = flagsG[(size_t)c*8 + q];
  for (int j = t; j < K_NMS*8; j += 512) maskS[j] = maskG[(size_t)c*K_NMS*8 + j];
  float sv = (t < K_NMS) ? aabb[((size_t)c*512 + t)*8 + 7] : -1.0f;
  ull vb = __ballot(sv > SCORE_THR);
  if (lane == 0) vbitsS[w] = vb;
  __syncthreads();
  if (w == 0){
    // every lane replicates the 512-bit suppressed set: no cross-lane ops
    ull rem[8];
#pragma unroll
    for (int q = 0; q < 8; ++q) rem[q] = ~vbitsS[q];   // sup0 = !valid
#pragma unroll
    for (int q = 0; q < 8; ++q){
      ull cand = flg[q] & ~rem[q];                     // alive rows that suppress
      while (cand){
        int b = __ffsll(cand) - 1;
        int i = q*64 + b;
#pragma unroll
        for (int z = 0; z < 8; ++z) rem[z] |= maskS[i*8 + z];
        ull above = (b < 63) ? (~0ull << (b + 1)) : 0ull;
        cand = flg[q] & ~rem[q] & above;               // masks only set bits > i
      }
    }
    if (lane == 0){
#pragma unroll
      for (int q = 0; q < 8; ++q) remS[q] = rem[q];
    }
  }
  __syncthreads();
  if (t < K_NMS)
    keep_out[c*K_NMS + t] = ((remS[t >> 6] >> (t & 63)) & 1ull) ? 0.0f : 1.0f;
}

// ---------------------------------------------------------------------------
extern "C" void kernel_launch(void* const* d_in, const int* in_sizes, int n_in,
                              void* d_out, int out_size, void* d_ws, size_t ws_size,
                              hipStream_t stream){
  Ptrs P;
  int off = 0;
  for (int L = 0; L < 4; ++L){
    P.cent[L] = (const float*)d_in[4*L + 0];
    P.bbox[L] = (const float*)d_in[4*L + 1];
    P.cls[L]  = (const float*)d_in[4*L + 2];
    P.pts[L]  = (const float*)d_in[4*L + 3];
    P.off[L]  = off;
    off += in_sizes[4*L + 0];
  }
  P.ntot = off;

  char* w = (char*)d_ws;
  size_t o = 0;
  auto alloc = [&](size_t bytes) -> char* {
    char* p = w + o;
    o = (o + bytes + 255) & ~(size_t)255;
    return p;
  };
  unsigned int* keys        = (unsigned int*)alloc((size_t)P.ntot * 4);
  unsigned int* hist        = (unsigned int*)alloc(4 * 2048 * 4);
  unsigned int* state       = (unsigned int*)alloc(4 * 2 * 4);
  unsigned int* cnts        = (unsigned int*)alloc(4 * 4);
  ull* lists                = (ull*)alloc((size_t)4 * LIST_CAP * 8);
  unsigned int* sidx        = (unsigned int*)alloc((size_t)POOL * 4);
  float* boxes_pool         = (float*)alloc((size_t)POOL * 6 * 4);
  float* scores_pool        = (float*)alloc((size_t)N_CLASSES * POOL * 4);
  float* aabb               = (float*)alloc((size_t)N_CLASSES * 512 * 8 * 4);
  ull* maskG                = (ull*)alloc((size_t)N_CLASSES * K_NMS * 8 * 8);
  ull* flagsG               = (ull*)alloc((size_t)N_CLASSES * 8 * 8);

  float* out = (float*)d_out;
  int grid = (P.ntot + 255) / 256;

  init_kernel<<<1, 256, 0, stream>>>(hist, state, cnts);
  compute_keys<<<grid, 256, 0, stream>>>(P, keys, hist);
  scan_level<<<1, 256, 0, stream>>>(hist, state, 0);
  hist_level<<<grid, 256, 0, stream>>>(P, keys, state, hist);
  scan_level<<<1, 256, 0, stream>>>(hist, state, 1);
  compact_kernel<<<grid, 256, 0, stream>>>(P, keys, state, cnts, lists);
  sort_idx<<<4, 1024, 0, stream>>>(lists, cnts, sidx);
  gather_decode<<<(POOL + 63)/64, 64, 0, stream>>>(P, sidx, boxes_pool, scores_pool);
  class_topk<<<N_CLASSES, 1024, 0, stream>>>(scores_pool, boxes_pool, out, aabb);
  nms_mask<<<dim3(8, N_CLASSES), 512, 0, stream>>>(aabb, maskG, flagsG);
  nms_greedy<<<N_CLASSES, 512, 0, stream>>>(aabb, maskG, flagsG, out + 72000);
}